// Round 14
// baseline (230.678 us; speedup 1.0000x reference)
//
#include <hip/hip_runtime.h>
#include <math.h>

#define B 128
#define C 576
#define H 28
#define W 28
#define HW 784
#define NPLANE (B * C)
#define RMROWS 34   // 3 ghost + 28 + 3 ghost
#define LOG2E 1.4426950408889634f

typedef float nfloat4 __attribute__((ext_vector_type(4)));

// sigmoid with log2e pre-folded into the argument: 1/(1+2^(-z))
__device__ __forceinline__ float sigm2(float z2) { return 1.f / (1.f + exp2f(-z2)); }

__device__ __forceinline__ float4 fmax4(float4 a, float4 b) {
    a.x = fmaxf(a.x, b.x); a.y = fmaxf(a.y, b.y);
    a.z = fmaxf(a.z, b.z); a.w = fmaxf(a.w, b.w);
    return a;
}

// horizontal 7-window max for 4 px: Mv center f4, Lv left f4, Rv right f4
__device__ __forceinline__ float4 hmax13(float4 Mv, float4 Lv, float4 Rv) {
    float mm   = fmaxf(fmaxf(Mv.x, Mv.y), fmaxf(Mv.z, Mv.w));
    float l23  = fmaxf(Lv.z, Lv.w);
    float l123 = fmaxf(Lv.y, l23);
    float r01  = fmaxf(Rv.x, Rv.y);
    float r012 = fmaxf(r01, Rv.z);
    float4 o;
    o.x = fmaxf(l123, mm);
    o.y = fmaxf(l23, fmaxf(mm, Rv.x));
    o.z = fmaxf(Lv.w, fmaxf(mm, r01));
    o.w = fmaxf(mm, r012);
    return o;
}

// full 64-lane sum via DPP (VALU-only, no LDS); total lands in lane 63
__device__ __forceinline__ float dpp_sum64(float v) {
    int t;
    t = __builtin_amdgcn_update_dpp(0, __float_as_int(v), 0x111, 0xf, 0xf, true);  v += __int_as_float(t);
    t = __builtin_amdgcn_update_dpp(0, __float_as_int(v), 0x112, 0xf, 0xf, true);  v += __int_as_float(t);
    t = __builtin_amdgcn_update_dpp(0, __float_as_int(v), 0x114, 0xf, 0xf, true);  v += __int_as_float(t);
    t = __builtin_amdgcn_update_dpp(0, __float_as_int(v), 0x118, 0xf, 0xf, true);  v += __int_as_float(t);
    t = __builtin_amdgcn_update_dpp(0, __float_as_int(v), 0x142, 0xa, 0xf, false); v += __int_as_float(t);
    t = __builtin_amdgcn_update_dpp(0, __float_as_int(v), 0x143, 0xc, 0xf, false); v += __int_as_float(t);
    return v;
}

// wave-internal LDS write->read ordering (same-wave DS ops are in-order;
// fence stops compiler reordering and drains outstanding LDS ops)
__device__ __forceinline__ void wave_lds_fence() {
    asm volatile("s_waitcnt lgkmcnt(0)" ::: "memory");
    __builtin_amdgcn_sched_barrier(0);
}

// ---------------------------------------------------------------------------
// K0: zero accumulators; build orientation masks ANGLE-MAJOR [6][784] in BF16.
// ---------------------------------------------------------------------------
__global__ void k0_init(unsigned short* __restrict__ masks16, float* __restrict__ acc) {
    int idx = blockIdx.x * 256 + threadIdx.x;
    if (idx < 6 * C) acc[idx] = 0.f;
    if (idx < 6 * HW) {
        int a = idx / HW;
        int p = idx - a * HW;
        int r = p / W;
        int col = p - r * W;
        const float degs[6] = {0.f, 30.f, 45.f, 60.f, 90.f, 135.f};
        float t = degs[a] * 0.017453292519943295f;
        float gy = -1.f + r * (2.f / 27.f);
        float gx = -1.f + col * (2.f / 27.f);
        float perp = gx * (-sinf(t)) + gy * cosf(t);
        float z = perp * (1.f / 0.3f);
        float m = expf(-0.5f * z * z);
        unsigned int u = __float_as_uint(m);
        unsigned int rnd = (u + 0x7fffu + ((u >> 16) & 1u)) >> 16;  // RNE bf16
        masks16[idx] = (unsigned short)rnd;
    }
}

// ---------------------------------------------------------------------------
// K1: one wave per plane; x staged inside rm's padded rows (union buffer).
//     Masks staged ONCE per block into LDS (bf16, 9.4 KB) — removes 24
//     redundant VMEM loads per wave; consumed via ds_read_b64 + unpack.
// ---------------------------------------------------------------------------
__global__ __launch_bounds__(256, 5) void k1_stats(
    const float* __restrict__ x,
    const float* __restrict__ h_w, const float* __restrict__ v_w,
    const float* __restrict__ f_w, const unsigned short* __restrict__ masks16,
    float* __restrict__ yh, float* __restrict__ yv,
    float* __restrict__ at, float* __restrict__ acc)
{
    const int tid = threadIdx.x;
    const int wvi = __builtin_amdgcn_readfirstlane(tid >> 6);  // wave-uniform
    const int l   = tid & 63;
    const int plane = blockIdx.x * 4 + wvi;
    const int c = plane % C;
    const float* xp = x + (size_t)plane * HW;

    __shared__ __align__(16) float uA[4][RMROWS * W];
    __shared__ __align__(16) float cpA[4][196];
    __shared__ __align__(16) float rpA[4][196];
    __shared__ __align__(16) unsigned short mlds[6 * HW];   // 9408 B, block-shared
    float* rm  = uA[wvi];
    float* sxv = rm + 3 * W;      // x rows 0..27 live at padded rows 3..30
    float* cp  = cpA[wvi];
    float* rp  = rpA[wvi];

    const int r0 = l / 7;        // 0..6 (valid for l<49)
    const int u  = l - r0 * 7;   // column group 0..6
    const int q  = u * 4;
    const int qL = u ? q - 4 : 0;
    const int qR = (u < 6) ? q + 4 : 24;
    const bool act = (l < 49);

    float4 Mv[4];
    float fs = 0.f, fss = 0.f;

    // issue x loads first (latency hides under mask staging + barrier)
    if (act) {
        #pragma unroll
        for (int k = 0; k < 4; ++k) Mv[k] = ((const float4*)xp)[l + 49 * k];
    }

    // stage bf16 masks into LDS: 9408 B = 588 uint4, all 256 threads
    {
        const uint4* gm = (const uint4*)masks16;
        uint4* lm = (uint4*)mlds;
        #pragma unroll
        for (int i = 0; i < 3; ++i) {
            int j = tid + i * 256;
            if (j < 588) lm[j] = gm[j];
        }
    }
    __syncthreads();

    // P0: stage x to LDS; col/row partials; orientation dots from LDS masks
    {
        float o0=0.f,o1=0.f,o2=0.f,o3=0.f,o4=0.f,o5=0.f;
        if (act) {
            float4 ca = make_float4(0.f, 0.f, 0.f, 0.f);
            float rw[4];
            const uint2* mp = (const uint2*)mlds;   // uint2 index = a*196 + unit
            #pragma unroll
            for (int k = 0; k < 4; ++k) {
                const int unit = l + 49 * k;
                float4 v = Mv[k];
                ((float4*)sxv)[unit] = v;
                ca.x += v.x; ca.y += v.y; ca.z += v.z; ca.w += v.w;
                rw[k] = (v.x + v.y) + (v.z + v.w);
                #pragma unroll
                for (int a = 0; a < 6; ++a) {
                    uint2 d = mp[a * 196 + unit];
                    float m0 = __uint_as_float(d.x << 16);
                    float m1 = __uint_as_float(d.x & 0xffff0000u);
                    float m2 = __uint_as_float(d.y << 16);
                    float m3 = __uint_as_float(d.y & 0xffff0000u);
                    float dot = v.x * m0 + v.y * m1 + v.z * m2 + v.w * m3;
                    if (a == 0) o0 += dot; else if (a == 1) o1 += dot;
                    else if (a == 2) o2 += dot; else if (a == 3) o3 += dot;
                    else if (a == 4) o4 += dot; else o5 += dot;
                }
            }
            ((float4*)cp)[l] = ca;
            ((float4*)rp)[l] = make_float4(rw[0], rw[1], rw[2], rw[3]);
        }
        // orientation reduction (o-regs die here; hides the LDS drain)
        o0 = dpp_sum64(o0); o1 = dpp_sum64(o1); o2 = dpp_sum64(o2);
        o3 = dpp_sum64(o3); o4 = dpp_sum64(o4); o5 = dpp_sum64(o5);
        if (l == 63) {
            const float s784 = LOG2E / (float)HW;
            float t = sigm2(o0 * s784) + sigm2(o1 * s784) + sigm2(o2 * s784)
                    + sigm2(o3 * s784) + sigm2(o4 * s784) + sigm2(o5 * s784);
            at[plane] = t * (1.f / 6.f);
        }
    }
    wave_lds_fence();

    // P1: horizontal 7-max; write in place over the row just read (+ ghosts)
    if (act) {
        #pragma unroll
        for (int k = 0; k < 4; ++k) {
            const int r = r0 + 7 * k;
            const float* row = sxv + r * W;
            float4 Lv = *(const float4*)(row + qL);
            float4 Rv = *(const float4*)(row + qR);
            float4 hv = hmax13(Mv[k], Lv, Rv);
            *(float4*)(rm + (r + 3) * W + q) = hv;
            if (k == 0 && r0 == 0) {
                *(float4*)(rm + 0 * W + q) = hv;
                *(float4*)(rm + 1 * W + q) = hv;
                *(float4*)(rm + 2 * W + q) = hv;
            }
            if (k == 3 && r0 == 6) {
                *(float4*)(rm + 31 * W + q) = hv;
                *(float4*)(rm + 32 * W + q) = hv;
                *(float4*)(rm + 33 * W + q) = hv;
            }
        }
    }
    wave_lds_fence();

    // P2: vertical 7-max -> RAW spot moments (fwc folded in once at the end)
    if (act) {
        #pragma unroll
        for (int k = 0; k < 4; ++k) {
            const int r = r0 + 7 * k;
            const float* vb = rm + r * W + q;
            float4 m = *(const float4*)vb;
            m = fmax4(m, *(const float4*)(vb + W));
            m = fmax4(m, *(const float4*)(vb + 2 * W));
            m = fmax4(m, *(const float4*)(vb + 3 * W));
            m = fmax4(m, *(const float4*)(vb + 4 * W));
            m = fmax4(m, *(const float4*)(vb + 5 * W));
            m = fmax4(m, *(const float4*)(vb + 6 * W));
            float s0 = m.x - Mv[k].x;
            float s1 = m.y - Mv[k].y;
            float s2 = m.z - Mv[k].z;
            float s3 = m.w - Mv[k].w;
            fs  += (s0 + s1) + (s2 + s3);
            fss += (s0 * s0 + s1 * s1) + (s2 * s2 + s3 * s3);
        }
    }

    // means assembly from partials (conflict-free strided reads)
    float ph_r = 0.f;
    float4 pvv = make_float4(0.f, 0.f, 0.f, 0.f);
    if (l < 28) {
        const int rr = l % 7, kk = l / 7;
        const float* rb = rp + rr * 28 + kk;
        float s = ((rb[0] + rb[4]) + (rb[8] + rb[12]))
                + ((rb[16] + rb[20]) + rb[24]);
        ph_r = s * (1.f / 28.f);
    }
    if (l < 7) {
        const float4* cb = (const float4*)cp;
        float4 a = cb[l];
        #pragma unroll
        for (int j = 1; j < 7; ++j) {
            float4 b = cb[l + 7 * j];
            a.x += b.x; a.y += b.y; a.z += b.z; a.w += b.w;
        }
        pvv.x = a.x * (1.f / 28.f); pvv.y = a.y * (1.f / 28.f);
        pvv.z = a.z * (1.f / 28.f); pvv.w = a.w * (1.f / 28.f);
    }

    // depthwise conv3 (zero-pad SAME) in-lane
    const float hw0 = h_w[c * 3], hw1 = h_w[c * 3 + 1], hw2 = h_w[c * 3 + 2];
    float yhv = 0.f;
    {
        float pm = __shfl_up(ph_r, 1);
        float pp = __shfl_down(ph_r, 1);
        if (l < 28) {
            float a = (l > 0) ? pm : 0.f;
            float d = (l < 27) ? pp : 0.f;
            yhv = hw0 * a + hw1 * ph_r + hw2 * d;
            yh[(size_t)plane * H + l] = yhv;
        }
    }
    const float vw0 = v_w[c * 3], vw1 = v_w[c * 3 + 1], vw2 = v_w[c * 3 + 2];
    float yvs = 0.f, yvq = 0.f;
    {
        float lf = __shfl_up(pvv.w, 1);
        float rg = __shfl_down(pvv.x, 1);
        if (l < 7) {
            float a0 = (l > 0) ? lf : 0.f;
            float d3 = (l < 6) ? rg : 0.f;
            float4 y;
            y.x = vw0 * a0    + vw1 * pvv.x + vw2 * pvv.y;
            y.y = vw0 * pvv.x + vw1 * pvv.y + vw2 * pvv.z;
            y.z = vw0 * pvv.y + vw1 * pvv.z + vw2 * pvv.w;
            y.w = vw0 * pvv.z + vw1 * pvv.w + vw2 * d3;
            ((float4*)(yv + (size_t)plane * W))[l] = y;
            yvs = (y.x + y.y) + (y.z + y.w);
            yvq = (y.x * y.x + y.y * y.y) + (y.z * y.z + y.w * y.w);
        }
    }
    float yhq = yhv * yhv;

    // 6 wave reductions on the VALU pipe
    fs = dpp_sum64(fs);  fss = dpp_sum64(fss);
    yhv = dpp_sum64(yhv); yhq = dpp_sum64(yhq);
    yvs = dpp_sum64(yvs); yvq = dpp_sum64(yvq);

    if (l == 63) {
        const float fwc = f_w[c];
        atomicAdd(&acc[0 * C + c], yhv);
        atomicAdd(&acc[1 * C + c], yhq);
        atomicAdd(&acc[2 * C + c], yvs);
        atomicAdd(&acc[3 * C + c], yvq);
        atomicAdd(&acc[4 * C + c], fs * fwc);
        atomicAdd(&acc[5 * C + c], fss * fwc * fwc);
    }
}

// ---------------------------------------------------------------------------
// K2: fold sums into per-channel BN scale/shift, stored padded [C][8].
//     log2e pre-folded so gates use exp2 directly; f-scale includes f_w.
// ---------------------------------------------------------------------------
__global__ __launch_bounds__(64) void k2_params(
    const float* __restrict__ acc, const float* __restrict__ f_w,
    const float* __restrict__ hg, const float* __restrict__ hb,
    const float* __restrict__ vg, const float* __restrict__ vb,
    const float* __restrict__ fg, const float* __restrict__ fb,
    float* __restrict__ params)
{
    int c = blockIdx.x * 64 + threadIdx.x;
    if (c >= C) return;
    const float inv_nh = 1.f / (float)(B * H);
    const float inv_nf = 1.f / (float)(B * HW);
    float m, v, sc;
    m = acc[c] * inv_nh;
    v = acc[C + c] * inv_nh - m * m;
    sc = hg[c] * rsqrtf(v + 1e-5f);
    params[c * 8 + 0] = sc * LOG2E; params[c * 8 + 1] = (hb[c] - m * sc) * LOG2E;

    m = acc[2 * C + c] * inv_nh;
    v = acc[3 * C + c] * inv_nh - m * m;
    sc = vg[c] * rsqrtf(v + 1e-5f);
    params[c * 8 + 2] = sc * LOG2E; params[c * 8 + 3] = (vb[c] - m * sc) * LOG2E;

    m = acc[4 * C + c] * inv_nf;
    v = acc[5 * C + c] * inv_nf - m * m;
    sc = fg[c] * rsqrtf(v + 1e-5f);
    params[c * 8 + 4] = sc * f_w[c] * LOG2E;      // acts on raw (max - x)
    params[c * 8 + 5] = (fb[c] - m * sc) * LOG2E;
}

// ---------------------------------------------------------------------------
// K3: one wave per plane; union buffer; all four gates; nt stores.
// ---------------------------------------------------------------------------
__global__ __launch_bounds__(256, 8) void k3_apply(
    const float* __restrict__ x,
    const float* __restrict__ yh, const float* __restrict__ yv,
    const float* __restrict__ at, const float* __restrict__ params,
    float* __restrict__ out)
{
    const int tid = threadIdx.x;
    const int wvi = __builtin_amdgcn_readfirstlane(tid >> 6);
    const int l   = tid & 63;
    const int plane = blockIdx.x * 4 + wvi;
    const int c = plane % C;
    const float* xp = x + (size_t)plane * HW;

    __shared__ __align__(16) float uA[4][RMROWS * W];
    float* rm  = uA[wvi];
    float* sxv = rm + 3 * W;

    const int r0 = l / 7;
    const int u  = l - r0 * 7;
    const int q  = u * 4;
    const int qL = u ? q - 4 : 0;
    const int qR = (u < 6) ? q + 4 : 24;
    const bool act = (l < 49);

    const float4 pA = *(const float4*)(params + c * 8);      // hsc,hsh,vsc,vsh (x log2e)
    const float2 pB = *(const float2*)(params + c * 8 + 4);  // fsc*fwc, fsh (x log2e)
    const float atv = at[plane];

    float4 Mv[4];

    // P0: load x into regs + padded LDS (single global read of x)
    if (act) {
        #pragma unroll
        for (int k = 0; k < 4; ++k) {
            const int unit = l + 49 * k;
            Mv[k] = ((const float4*)xp)[unit];
            ((float4*)sxv)[unit] = Mv[k];
        }
    }
    wave_lds_fence();

    // P1: horizontal 7-max in place (+ ghosts)
    if (act) {
        #pragma unroll
        for (int k = 0; k < 4; ++k) {
            const int r = r0 + 7 * k;
            const float* row = sxv + r * W;
            float4 Lv = *(const float4*)(row + qL);
            float4 Rv = *(const float4*)(row + qR);
            float4 hv = hmax13(Mv[k], Lv, Rv);
            *(float4*)(rm + (r + 3) * W + q) = hv;
            if (k == 0 && r0 == 0) {
                *(float4*)(rm + 0 * W + q) = hv;
                *(float4*)(rm + 1 * W + q) = hv;
                *(float4*)(rm + 2 * W + q) = hv;
            }
            if (k == 3 && r0 == 6) {
                *(float4*)(rm + 31 * W + q) = hv;
                *(float4*)(rm + 32 * W + q) = hv;
                *(float4*)(rm + 33 * W + q) = hv;
            }
        }
    }
    wave_lds_fence();

    // P2: vertical 7-max + gates + nontemporal store
    if (act) {
        float4 yv4 = ((const float4*)(yv + (size_t)plane * W))[u];
        float4 av;
        av.x = sigm2(pA.z * yv4.x + pA.w);
        av.y = sigm2(pA.z * yv4.y + pA.w);
        av.z = sigm2(pA.z * yv4.z + pA.w);
        av.w = sigm2(pA.z * yv4.w + pA.w);
        nfloat4* op = (nfloat4*)(out + (size_t)plane * HW);
        #pragma unroll
        for (int k = 0; k < 4; ++k) {
            const int r = r0 + 7 * k;
            const float* vb = rm + r * W + q;
            float4 m = *(const float4*)vb;
            m = fmax4(m, *(const float4*)(vb + W));
            m = fmax4(m, *(const float4*)(vb + 2 * W));
            m = fmax4(m, *(const float4*)(vb + 3 * W));
            m = fmax4(m, *(const float4*)(vb + 4 * W));
            m = fmax4(m, *(const float4*)(vb + 5 * W));
            m = fmax4(m, *(const float4*)(vb + 6 * W));
            float ahk = sigm2(pA.x * yh[(size_t)plane * H + r] + pA.y) * atv;
            nfloat4 o;
            o.x = Mv[k].x * ahk * av.x * sigm2(fmaf(pB.x, m.x, fmaf(-pB.x, Mv[k].x, pB.y)));
            o.y = Mv[k].y * ahk * av.y * sigm2(fmaf(pB.x, m.y, fmaf(-pB.x, Mv[k].y, pB.y)));
            o.z = Mv[k].z * ahk * av.z * sigm2(fmaf(pB.x, m.z, fmaf(-pB.x, Mv[k].z, pB.y)));
            o.w = Mv[k].w * ahk * av.w * sigm2(fmaf(pB.x, m.w, fmaf(-pB.x, Mv[k].w, pB.y)));
            __builtin_nontemporal_store(o, &op[l + 49 * k]);
        }
    }
}

// ---------------------------------------------------------------------------
extern "C" void kernel_launch(void* const* d_in, const int* in_sizes, int n_in,
                              void* d_out, int out_size, void* d_ws, size_t ws_size,
                              hipStream_t stream) {
    const float* x   = (const float*)d_in[0];
    const float* h_w = (const float*)d_in[1];
    const float* h_g = (const float*)d_in[2];
    const float* h_b = (const float*)d_in[3];
    const float* v_w = (const float*)d_in[4];
    const float* v_g = (const float*)d_in[5];
    const float* v_b = (const float*)d_in[6];
    const float* f_w = (const float*)d_in[7];
    const float* f_g = (const float*)d_in[8];
    const float* f_b = (const float*)d_in[9];
    float* out = (float*)d_out;
    float* ws = (float*)d_ws;

    // workspace layout (floats)
    unsigned short* masks16 = (unsigned short*)ws;  // 6*784 bf16 = 9408 B (2352 floats' worth)
    float* acc    = ws + 2352;          // 6*576  = 3456
    float* params = ws + 5808;          // 576*8  = 4608
    float* at     = ws + 10416;         // B*C    = 73728
    float* yh     = ws + 84144;         // B*C*H  = 2064384
    float* yv     = ws + 2148528;       // B*C*W  = 2064384

    k0_init<<<19, 256, 0, stream>>>(masks16, acc);
    k1_stats<<<NPLANE / 4, 256, 0, stream>>>(x, h_w, v_w, f_w, masks16, yh, yv, at, acc);
    k2_params<<<9, 64, 0, stream>>>(acc, f_w, h_g, h_b, v_g, v_b, f_g, f_b, params);
    k3_apply<<<NPLANE / 4, 256, 0, stream>>>(x, yh, yv, at, params, out);
}

// Round 16
// 176.495 us; speedup vs baseline: 1.3070x; 1.3070x over previous
//
#include <hip/hip_runtime.h>
#include <math.h>

#define B 128
#define C 576
#define H 28
#define W 28
#define HW 784
#define NPLANE (B * C)
#define RMROWS 34   // 3 ghost + 28 + 3 ghost
#define LOG2E 1.4426950408889634f

typedef float nfloat4 __attribute__((ext_vector_type(4)));
typedef _Float16 half2v __attribute__((ext_vector_type(2)));

// sigmoid with log2e pre-folded into the argument: 1/(1+2^(-z))
__device__ __forceinline__ float sigm2(float z2) { return 1.f / (1.f + exp2f(-z2)); }

__device__ __forceinline__ float4 fmax4(float4 a, float4 b) {
    a.x = fmaxf(a.x, b.x); a.y = fmaxf(a.y, b.y);
    a.z = fmaxf(a.z, b.z); a.w = fmaxf(a.w, b.w);
    return a;
}

// horizontal 7-window max for 4 px: Mv center f4, Lv left f4, Rv right f4
__device__ __forceinline__ float4 hmax13(float4 Mv, float4 Lv, float4 Rv) {
    float mm   = fmaxf(fmaxf(Mv.x, Mv.y), fmaxf(Mv.z, Mv.w));
    float l23  = fmaxf(Lv.z, Lv.w);
    float l123 = fmaxf(Lv.y, l23);
    float r01  = fmaxf(Rv.x, Rv.y);
    float r012 = fmaxf(r01, Rv.z);
    float4 o;
    o.x = fmaxf(l123, mm);
    o.y = fmaxf(l23, fmaxf(mm, Rv.x));
    o.z = fmaxf(Lv.w, fmaxf(mm, r01));
    o.w = fmaxf(mm, r012);
    return o;
}

// full 64-lane sum via DPP (VALU-only, no LDS); total lands in lane 63
__device__ __forceinline__ float dpp_sum64(float v) {
    int t;
    t = __builtin_amdgcn_update_dpp(0, __float_as_int(v), 0x111, 0xf, 0xf, true);  v += __int_as_float(t);
    t = __builtin_amdgcn_update_dpp(0, __float_as_int(v), 0x112, 0xf, 0xf, true);  v += __int_as_float(t);
    t = __builtin_amdgcn_update_dpp(0, __float_as_int(v), 0x114, 0xf, 0xf, true);  v += __int_as_float(t);
    t = __builtin_amdgcn_update_dpp(0, __float_as_int(v), 0x118, 0xf, 0xf, true);  v += __int_as_float(t);
    t = __builtin_amdgcn_update_dpp(0, __float_as_int(v), 0x142, 0xa, 0xf, false); v += __int_as_float(t);
    t = __builtin_amdgcn_update_dpp(0, __float_as_int(v), 0x143, 0xc, 0xf, false); v += __int_as_float(t);
    return v;
}

// wave-internal LDS write->read ordering (same-wave DS ops are in-order;
// fence stops compiler reordering and drains outstanding LDS ops)
__device__ __forceinline__ void wave_lds_fence() {
    asm volatile("s_waitcnt lgkmcnt(0)" ::: "memory");
    __builtin_amdgcn_sched_barrier(0);
}

// accumulate 4-elem f16 dot into f32
__device__ __forceinline__ float dot4h(half2v vlo, half2v vhi, uint2 md, float acc) {
    half2v mlo = __builtin_bit_cast(half2v, md.x);
    half2v mhi = __builtin_bit_cast(half2v, md.y);
#if __has_builtin(__builtin_amdgcn_fdot2)
    acc = __builtin_amdgcn_fdot2(vlo, mlo, acc, false);
    acc = __builtin_amdgcn_fdot2(vhi, mhi, acc, false);
#else
    acc += (float)vlo.x * (float)mlo.x + (float)vlo.y * (float)mlo.y
         + (float)vhi.x * (float)mhi.x + (float)vhi.y * (float)mhi.y;
#endif
    return acc;
}

// ---------------------------------------------------------------------------
// K0: zero accumulators; f16 masks for angles {30,45,60,135} only
//     (0 and 90 are separable and handled analytically in K1).
// ---------------------------------------------------------------------------
__global__ void k0_init(_Float16* __restrict__ masksf16, float* __restrict__ acc) {
    int idx = blockIdx.x * 256 + threadIdx.x;
    if (idx < 6 * C) acc[idx] = 0.f;
    if (idx < 4 * HW) {
        int a = idx / HW;
        int p = idx - a * HW;
        int r = p / W;
        int col = p - r * W;
        const float degs[4] = {30.f, 45.f, 60.f, 135.f};
        float t = degs[a] * 0.017453292519943295f;
        float gy = -1.f + r * (2.f / 27.f);
        float gx = -1.f + col * (2.f / 27.f);
        float perp = gx * (-sinf(t)) + gy * cosf(t);
        float z = perp * (1.f / 0.3f);
        masksf16[idx] = (_Float16)expf(-0.5f * z * z);
    }
}

// ---------------------------------------------------------------------------
// K1: one wave per plane; x staged inside rm's padded rows (union buffer).
//     Orientation: 4 angles via f16 fdot2 (half the bytes/instrs), angles
//     0/90 analytically from row/col sums.
// ---------------------------------------------------------------------------
__global__ __launch_bounds__(256, 7) void k1_stats(
    const float* __restrict__ x,
    const float* __restrict__ h_w, const float* __restrict__ v_w,
    const float* __restrict__ f_w, const _Float16* __restrict__ masksf16,
    float* __restrict__ yh, float* __restrict__ yv,
    float* __restrict__ at, float* __restrict__ acc)
{
    const int tid = threadIdx.x;
    const int wvi = __builtin_amdgcn_readfirstlane(tid >> 6);  // wave-uniform
    const int l   = tid & 63;
    const int plane = blockIdx.x * 4 + wvi;
    const int c = plane % C;
    const float* xp = x + (size_t)plane * HW;

    __shared__ __align__(16) float uA[4][RMROWS * W];
    __shared__ __align__(16) float cpA[4][196];
    __shared__ __align__(16) float rpA[4][196];
    float* rm  = uA[wvi];
    float* sxv = rm + 3 * W;      // x rows 0..27 live at padded rows 3..30
    float* cp  = cpA[wvi];
    float* rp  = rpA[wvi];

    const int r0 = l / 7;        // 0..6 (valid for l<49)
    const int u  = l - r0 * 7;   // column group 0..6
    const int q  = u * 4;
    const int qL = u ? q - 4 : 0;
    const int qR = (u < 6) ? q + 4 : 24;
    const bool act = (l < 49);

    const uint2* mk2p = (const uint2*)masksf16;   // [4 angles][196] uint2

    float4 Mv[4];
    float fs = 0.f, fss = 0.f;
    float o30 = 0.f, o45 = 0.f, o60 = 0.f, o135 = 0.f;

    // P0: load x into regs + padded LDS; col/row partials; 4-angle f16 dots
    if (act) {
        float4 ca = make_float4(0.f, 0.f, 0.f, 0.f);
        float rw[4];
        #pragma unroll
        for (int k = 0; k < 4; ++k) {
            const int unit = l + 49 * k;
            float4 v = ((const float4*)xp)[unit];
            Mv[k] = v;
            ((float4*)sxv)[unit] = v;
            ca.x += v.x; ca.y += v.y; ca.z += v.z; ca.w += v.w;
            rw[k] = (v.x + v.y) + (v.z + v.w);
            half2v vlo = __builtin_bit_cast(half2v, __builtin_amdgcn_cvt_pkrtz(v.x, v.y));
            half2v vhi = __builtin_bit_cast(half2v, __builtin_amdgcn_cvt_pkrtz(v.z, v.w));
            o30  = dot4h(vlo, vhi, mk2p[unit],           o30);
            o45  = dot4h(vlo, vhi, mk2p[196 + unit],     o45);
            o60  = dot4h(vlo, vhi, mk2p[2 * 196 + unit], o60);
            o135 = dot4h(vlo, vhi, mk2p[3 * 196 + unit], o135);
        }
        ((float4*)cp)[l] = ca;
        ((float4*)rp)[l] = make_float4(rw[0], rw[1], rw[2], rw[3]);
    }
    wave_lds_fence();

    // P1: horizontal 7-max; write in place over the row just read (+ ghosts)
    if (act) {
        #pragma unroll
        for (int k = 0; k < 4; ++k) {
            const int r = r0 + 7 * k;
            const float* row = sxv + r * W;
            float4 Lv = *(const float4*)(row + qL);
            float4 Rv = *(const float4*)(row + qR);
            float4 hv = hmax13(Mv[k], Lv, Rv);
            *(float4*)(rm + (r + 3) * W + q) = hv;
            if (k == 0 && r0 == 0) {
                *(float4*)(rm + 0 * W + q) = hv;
                *(float4*)(rm + 1 * W + q) = hv;
                *(float4*)(rm + 2 * W + q) = hv;
            }
            if (k == 3 && r0 == 6) {
                *(float4*)(rm + 31 * W + q) = hv;
                *(float4*)(rm + 32 * W + q) = hv;
                *(float4*)(rm + 33 * W + q) = hv;
            }
        }
    }
    wave_lds_fence();

    // P2: vertical 7-max -> RAW spot moments (fwc folded in once at the end)
    if (act) {
        #pragma unroll
        for (int k = 0; k < 4; ++k) {
            const int r = r0 + 7 * k;
            const float* vb = rm + r * W + q;
            float4 m = *(const float4*)vb;
            m = fmax4(m, *(const float4*)(vb + W));
            m = fmax4(m, *(const float4*)(vb + 2 * W));
            m = fmax4(m, *(const float4*)(vb + 3 * W));
            m = fmax4(m, *(const float4*)(vb + 4 * W));
            m = fmax4(m, *(const float4*)(vb + 5 * W));
            m = fmax4(m, *(const float4*)(vb + 6 * W));
            float s0 = m.x - Mv[k].x;
            float s1 = m.y - Mv[k].y;
            float s2 = m.z - Mv[k].z;
            float s3 = m.w - Mv[k].w;
            fs  += (s0 + s1) + (s2 + s3);
            fss += (s0 * s0 + s1 * s1) + (s2 * s2 + s3 * s3);
        }
    }

    // row/col sums on lanes 0-27 (conflict-free strided reads)
    float s_row = 0.f, colsum = 0.f, ph_r = 0.f;
    if (l < 28) {
        const int rr = l % 7, kk = l / 7;
        const float* rb = rp + rr * 28 + kk;
        s_row = ((rb[0] + rb[4]) + (rb[8] + rb[12]))
              + ((rb[16] + rb[20]) + rb[24]);
        ph_r = s_row * (1.f / 28.f);
        colsum = ((cp[l] + cp[l + 28]) + (cp[l + 56] + cp[l + 84]))
               + ((cp[l + 112] + cp[l + 140]) + cp[l + 168]);
    }

    // separable angles 0 / 90: same 1-D Gaussian profile on the same grid
    float g = -1.f + (float)l * (2.f / 27.f);
    float mg = exp2f(-8.014972687f * g * g);   // (0.5/0.09)*log2e
    float r0s  = (l < 28) ? s_row  * mg : 0.f;
    float r90s = (l < 28) ? colsum * mg : 0.f;

    // depthwise conv3 (zero-pad SAME) in-lane — rows
    const float hw0 = h_w[c * 3], hw1 = h_w[c * 3 + 1], hw2 = h_w[c * 3 + 2];
    float yhv = 0.f;
    {
        float pm = __shfl_up(ph_r, 1);
        float pp = __shfl_down(ph_r, 1);
        if (l < 28) {
            float a = (l > 0) ? pm : 0.f;
            float d = (l < 27) ? pp : 0.f;
            yhv = hw0 * a + hw1 * ph_r + hw2 * d;
            yh[(size_t)plane * H + l] = yhv;
        }
    }
    // depthwise conv3 — cols (mirrors the row path on lanes 0-27)
    const float vw0 = v_w[c * 3], vw1 = v_w[c * 3 + 1], vw2 = v_w[c * 3 + 2];
    float yvv = 0.f;
    {
        float pvm = colsum * (1.f / 28.f);
        float pm2 = __shfl_up(pvm, 1);
        float pp2 = __shfl_down(pvm, 1);
        if (l < 28) {
            float a = (l > 0) ? pm2 : 0.f;
            float d = (l < 27) ? pp2 : 0.f;
            yvv = vw0 * a + vw1 * pvm + vw2 * d;
            yv[(size_t)plane * W + l] = yvv;
        }
    }
    float yhq = yhv * yhv;
    float yvq = yvv * yvv;

    // 12 wave reductions, all on the VALU pipe
    fs  = dpp_sum64(fs);   fss  = dpp_sum64(fss);
    yhv = dpp_sum64(yhv);  yhq  = dpp_sum64(yhq);
    float yvs = dpp_sum64(yvv); yvq = dpp_sum64(yvq);
    o30 = dpp_sum64(o30);  o45  = dpp_sum64(o45);
    o60 = dpp_sum64(o60);  o135 = dpp_sum64(o135);
    r0s = dpp_sum64(r0s);  r90s = dpp_sum64(r90s);

    if (l == 63) {
        const float s784 = LOG2E / (float)HW;
        float t = sigm2(r0s * s784) + sigm2(o30 * s784) + sigm2(o45 * s784)
                + sigm2(o60 * s784) + sigm2(r90s * s784) + sigm2(o135 * s784);
        at[plane] = t * (1.f / 6.f);
        const float fwc = f_w[c];
        atomicAdd(&acc[0 * C + c], yhv);
        atomicAdd(&acc[1 * C + c], yhq);
        atomicAdd(&acc[2 * C + c], yvs);
        atomicAdd(&acc[3 * C + c], yvq);
        atomicAdd(&acc[4 * C + c], fs * fwc);
        atomicAdd(&acc[5 * C + c], fss * fwc * fwc);
    }
}

// ---------------------------------------------------------------------------
// K2: fold sums into per-channel BN scale/shift, stored padded [C][8].
//     log2e pre-folded so gates use exp2 directly; f-scale includes f_w.
// ---------------------------------------------------------------------------
__global__ __launch_bounds__(64) void k2_params(
    const float* __restrict__ acc, const float* __restrict__ f_w,
    const float* __restrict__ hg, const float* __restrict__ hb,
    const float* __restrict__ vg, const float* __restrict__ vb,
    const float* __restrict__ fg, const float* __restrict__ fb,
    float* __restrict__ params)
{
    int c = blockIdx.x * 64 + threadIdx.x;
    if (c >= C) return;
    const float inv_nh = 1.f / (float)(B * H);
    const float inv_nf = 1.f / (float)(B * HW);
    float m, v, sc;
    m = acc[c] * inv_nh;
    v = acc[C + c] * inv_nh - m * m;
    sc = hg[c] * rsqrtf(v + 1e-5f);
    params[c * 8 + 0] = sc * LOG2E; params[c * 8 + 1] = (hb[c] - m * sc) * LOG2E;

    m = acc[2 * C + c] * inv_nh;
    v = acc[3 * C + c] * inv_nh - m * m;
    sc = vg[c] * rsqrtf(v + 1e-5f);
    params[c * 8 + 2] = sc * LOG2E; params[c * 8 + 3] = (vb[c] - m * sc) * LOG2E;

    m = acc[4 * C + c] * inv_nf;
    v = acc[5 * C + c] * inv_nf - m * m;
    sc = fg[c] * rsqrtf(v + 1e-5f);
    params[c * 8 + 4] = sc * f_w[c] * LOG2E;      // acts on raw (max - x)
    params[c * 8 + 5] = (fb[c] - m * sc) * LOG2E;
}

// ---------------------------------------------------------------------------
// K3: one wave per plane; union buffer; all four gates; nt stores.
// ---------------------------------------------------------------------------
__global__ __launch_bounds__(256, 8) void k3_apply(
    const float* __restrict__ x,
    const float* __restrict__ yh, const float* __restrict__ yv,
    const float* __restrict__ at, const float* __restrict__ params,
    float* __restrict__ out)
{
    const int tid = threadIdx.x;
    const int wvi = __builtin_amdgcn_readfirstlane(tid >> 6);
    const int l   = tid & 63;
    const int plane = blockIdx.x * 4 + wvi;
    const int c = plane % C;
    const float* xp = x + (size_t)plane * HW;

    __shared__ __align__(16) float uA[4][RMROWS * W];
    float* rm  = uA[wvi];
    float* sxv = rm + 3 * W;

    const int r0 = l / 7;
    const int u  = l - r0 * 7;
    const int q  = u * 4;
    const int qL = u ? q - 4 : 0;
    const int qR = (u < 6) ? q + 4 : 24;
    const bool act = (l < 49);

    const float4 pA = *(const float4*)(params + c * 8);      // hsc,hsh,vsc,vsh (x log2e)
    const float2 pB = *(const float2*)(params + c * 8 + 4);  // fsc*fwc, fsh (x log2e)
    const float atv = at[plane];

    float4 Mv[4];

    // P0: load x into regs + padded LDS (single global read of x)
    if (act) {
        #pragma unroll
        for (int k = 0; k < 4; ++k) {
            const int unit = l + 49 * k;
            Mv[k] = ((const float4*)xp)[unit];
            ((float4*)sxv)[unit] = Mv[k];
        }
    }
    wave_lds_fence();

    // P1: horizontal 7-max in place (+ ghosts)
    if (act) {
        #pragma unroll
        for (int k = 0; k < 4; ++k) {
            const int r = r0 + 7 * k;
            const float* row = sxv + r * W;
            float4 Lv = *(const float4*)(row + qL);
            float4 Rv = *(const float4*)(row + qR);
            float4 hv = hmax13(Mv[k], Lv, Rv);
            *(float4*)(rm + (r + 3) * W + q) = hv;
            if (k == 0 && r0 == 0) {
                *(float4*)(rm + 0 * W + q) = hv;
                *(float4*)(rm + 1 * W + q) = hv;
                *(float4*)(rm + 2 * W + q) = hv;
            }
            if (k == 3 && r0 == 6) {
                *(float4*)(rm + 31 * W + q) = hv;
                *(float4*)(rm + 32 * W + q) = hv;
                *(float4*)(rm + 33 * W + q) = hv;
            }
        }
    }
    wave_lds_fence();

    // P2: vertical 7-max + gates + nontemporal store
    if (act) {
        float4 yv4;
        yv4.x = yv[(size_t)plane * W + q];
        yv4.y = yv[(size_t)plane * W + q + 1];
        yv4.z = yv[(size_t)plane * W + q + 2];
        yv4.w = yv[(size_t)plane * W + q + 3];
        float4 av;
        av.x = sigm2(pA.z * yv4.x + pA.w);
        av.y = sigm2(pA.z * yv4.y + pA.w);
        av.z = sigm2(pA.z * yv4.z + pA.w);
        av.w = sigm2(pA.z * yv4.w + pA.w);
        nfloat4* op = (nfloat4*)(out + (size_t)plane * HW);
        #pragma unroll
        for (int k = 0; k < 4; ++k) {
            const int r = r0 + 7 * k;
            const float* vb = rm + r * W + q;
            float4 m = *(const float4*)vb;
            m = fmax4(m, *(const float4*)(vb + W));
            m = fmax4(m, *(const float4*)(vb + 2 * W));
            m = fmax4(m, *(const float4*)(vb + 3 * W));
            m = fmax4(m, *(const float4*)(vb + 4 * W));
            m = fmax4(m, *(const float4*)(vb + 5 * W));
            m = fmax4(m, *(const float4*)(vb + 6 * W));
            float ahk = sigm2(pA.x * yh[(size_t)plane * H + r] + pA.y) * atv;
            nfloat4 o;
            o.x = Mv[k].x * ahk * av.x * sigm2(fmaf(pB.x, m.x, fmaf(-pB.x, Mv[k].x, pB.y)));
            o.y = Mv[k].y * ahk * av.y * sigm2(fmaf(pB.x, m.y, fmaf(-pB.x, Mv[k].y, pB.y)));
            o.z = Mv[k].z * ahk * av.z * sigm2(fmaf(pB.x, m.z, fmaf(-pB.x, Mv[k].z, pB.y)));
            o.w = Mv[k].w * ahk * av.w * sigm2(fmaf(pB.x, m.w, fmaf(-pB.x, Mv[k].w, pB.y)));
            __builtin_nontemporal_store(o, &op[l + 49 * k]);
        }
    }
}

// ---------------------------------------------------------------------------
extern "C" void kernel_launch(void* const* d_in, const int* in_sizes, int n_in,
                              void* d_out, int out_size, void* d_ws, size_t ws_size,
                              hipStream_t stream) {
    const float* x   = (const float*)d_in[0];
    const float* h_w = (const float*)d_in[1];
    const float* h_g = (const float*)d_in[2];
    const float* h_b = (const float*)d_in[3];
    const float* v_w = (const float*)d_in[4];
    const float* v_g = (const float*)d_in[5];
    const float* v_b = (const float*)d_in[6];
    const float* f_w = (const float*)d_in[7];
    const float* f_g = (const float*)d_in[8];
    const float* f_b = (const float*)d_in[9];
    float* out = (float*)d_out;
    float* ws = (float*)d_ws;

    // workspace layout (floats)
    _Float16* masksf16 = (_Float16*)ws;  // 4*784 f16 = 6272 B (1568 floats)
    float* acc    = ws + 1568;           // 6*576  = 3456
    float* params = ws + 5024;           // 576*8  = 4608
    float* at     = ws + 9632;           // B*C    = 73728
    float* yh     = ws + 83360;          // B*C*H  = 2064384
    float* yv     = ws + 2147744;        // B*C*W  = 2064384

    k0_init<<<14, 256, 0, stream>>>(masksf16, acc);
    k1_stats<<<NPLANE / 4, 256, 0, stream>>>(x, h_w, v_w, f_w, masksf16, yh, yv, at, acc);
    k2_params<<<9, 64, 0, stream>>>(acc, f_w, h_g, h_b, v_g, v_b, f_g, f_b, params);
    k3_apply<<<NPLANE / 4, 256, 0, stream>>>(x, yh, yv, at, params, out);
}

// Round 17
// 172.495 us; speedup vs baseline: 1.3373x; 1.0232x over previous
//
#include <hip/hip_runtime.h>
#include <math.h>

#define B 128
#define C 576
#define H 28
#define W 28
#define HW 784
#define NPLANE (B * C)
#define RMROWS 34   // 3 ghost + 28 + 3 ghost
#define LOG2E 1.4426950408889634f

typedef float nfloat4 __attribute__((ext_vector_type(4)));
typedef _Float16 half2v __attribute__((ext_vector_type(2)));

// sigmoid with log2e pre-folded into the argument: 1/(1+2^(-z))
__device__ __forceinline__ float sigm2(float z2) { return 1.f / (1.f + exp2f(-z2)); }

__device__ __forceinline__ float4 fmax4(float4 a, float4 b) {
    a.x = fmaxf(a.x, b.x); a.y = fmaxf(a.y, b.y);
    a.z = fmaxf(a.z, b.z); a.w = fmaxf(a.w, b.w);
    return a;
}

// horizontal 7-window max for 4 px: Mv center f4, Lv left f4, Rv right f4
__device__ __forceinline__ float4 hmax13(float4 Mv, float4 Lv, float4 Rv) {
    float mm   = fmaxf(fmaxf(Mv.x, Mv.y), fmaxf(Mv.z, Mv.w));
    float l23  = fmaxf(Lv.z, Lv.w);
    float l123 = fmaxf(Lv.y, l23);
    float r01  = fmaxf(Rv.x, Rv.y);
    float r012 = fmaxf(r01, Rv.z);
    float4 o;
    o.x = fmaxf(l123, mm);
    o.y = fmaxf(l23, fmaxf(mm, Rv.x));
    o.z = fmaxf(Lv.w, fmaxf(mm, r01));
    o.w = fmaxf(mm, r012);
    return o;
}

// full 64-lane sum via DPP; total lands in lane 63
__device__ __forceinline__ float dpp_sum64(float v) {
    int t;
    t = __builtin_amdgcn_update_dpp(0, __float_as_int(v), 0x111, 0xf, 0xf, true);  v += __int_as_float(t);
    t = __builtin_amdgcn_update_dpp(0, __float_as_int(v), 0x112, 0xf, 0xf, true);  v += __int_as_float(t);
    t = __builtin_amdgcn_update_dpp(0, __float_as_int(v), 0x114, 0xf, 0xf, true);  v += __int_as_float(t);
    t = __builtin_amdgcn_update_dpp(0, __float_as_int(v), 0x118, 0xf, 0xf, true);  v += __int_as_float(t);
    t = __builtin_amdgcn_update_dpp(0, __float_as_int(v), 0x142, 0xa, 0xf, false); v += __int_as_float(t);
    t = __builtin_amdgcn_update_dpp(0, __float_as_int(v), 0x143, 0xc, 0xf, false); v += __int_as_float(t);
    return v;
}

// per-32-half sum via DPP (5 steps): lane31 = sum(0..31), lane63 = sum(32..63)
__device__ __forceinline__ float dpp_sum32(float v) {
    int t;
    t = __builtin_amdgcn_update_dpp(0, __float_as_int(v), 0x111, 0xf, 0xf, true);  v += __int_as_float(t);
    t = __builtin_amdgcn_update_dpp(0, __float_as_int(v), 0x112, 0xf, 0xf, true);  v += __int_as_float(t);
    t = __builtin_amdgcn_update_dpp(0, __float_as_int(v), 0x114, 0xf, 0xf, true);  v += __int_as_float(t);
    t = __builtin_amdgcn_update_dpp(0, __float_as_int(v), 0x118, 0xf, 0xf, true);  v += __int_as_float(t);
    t = __builtin_amdgcn_update_dpp(0, __float_as_int(v), 0x142, 0xa, 0xf, false); v += __int_as_float(t);
    return v;
}

__device__ __forceinline__ float rlane(float v, int n) {
    return __int_as_float(__builtin_amdgcn_readlane(__float_as_int(v), n));
}

// wave-internal LDS write->read ordering
__device__ __forceinline__ void wave_lds_fence() {
    asm volatile("s_waitcnt lgkmcnt(0)" ::: "memory");
    __builtin_amdgcn_sched_barrier(0);
}

// accumulate 4-elem f16 dot into f32
__device__ __forceinline__ float dot4h(half2v vlo, half2v vhi, uint2 md, float acc) {
    half2v mlo = __builtin_bit_cast(half2v, md.x);
    half2v mhi = __builtin_bit_cast(half2v, md.y);
#if __has_builtin(__builtin_amdgcn_fdot2)
    acc = __builtin_amdgcn_fdot2(vlo, mlo, acc, false);
    acc = __builtin_amdgcn_fdot2(vhi, mhi, acc, false);
#else
    acc += (float)vlo.x * (float)mlo.x + (float)vlo.y * (float)mlo.y
         + (float)vhi.x * (float)mhi.x + (float)vhi.y * (float)mhi.y;
#endif
    return acc;
}

// ---------------------------------------------------------------------------
// K0: zero accumulators; f16 masks for angles {30,45,60,135} only.
// ---------------------------------------------------------------------------
__global__ void k0_init(_Float16* __restrict__ masksf16, float* __restrict__ acc) {
    int idx = blockIdx.x * 256 + threadIdx.x;
    if (idx < 6 * C) acc[idx] = 0.f;
    if (idx < 4 * HW) {
        int a = idx / HW;
        int p = idx - a * HW;
        int r = p / W;
        int col = p - r * W;
        const float degs[4] = {30.f, 45.f, 60.f, 135.f};
        float t = degs[a] * 0.017453292519943295f;
        float gy = -1.f + r * (2.f / 27.f);
        float gx = -1.f + col * (2.f / 27.f);
        float perp = gx * (-sinf(t)) + gy * cosf(t);
        float z = perp * (1.f / 0.3f);
        masksf16[idx] = (_Float16)expf(-0.5f * z * z);
    }
}

// ---------------------------------------------------------------------------
// K1: one wave per plane. Row stats on lanes 0-27, col stats on lanes 32-59
//     (packed half-wave reductions); 4-angle f16 dots; 0/90 separable.
// ---------------------------------------------------------------------------
__global__ __launch_bounds__(256, 7) void k1_stats(
    const float* __restrict__ x,
    const float* __restrict__ h_w, const float* __restrict__ v_w,
    const float* __restrict__ f_w, const _Float16* __restrict__ masksf16,
    float* __restrict__ yh, float* __restrict__ yv,
    float* __restrict__ at, float* __restrict__ acc)
{
    const int tid = threadIdx.x;
    const int wvi = __builtin_amdgcn_readfirstlane(tid >> 6);
    const int l   = tid & 63;
    const int plane = blockIdx.x * 4 + wvi;
    const int c = plane % C;
    const float* xp = x + (size_t)plane * HW;

    __shared__ __align__(16) float uA[4][RMROWS * W];
    __shared__ __align__(16) float cpA[4][196];
    __shared__ __align__(16) float rpA[4][196];
    float* rm  = uA[wvi];
    float* sxv = rm + 3 * W;
    float* cp  = cpA[wvi];
    float* rp  = rpA[wvi];

    const int r0 = l / 7;
    const int u  = l - r0 * 7;
    const int q  = u * 4;
    const int qL = u ? q - 4 : 0;
    const int qR = (u < 6) ? q + 4 : 24;
    const bool act = (l < 49);

    const uint2* mk2p = (const uint2*)masksf16;

    float4 Mv[4];
    float fs = 0.f, fss = 0.f;
    float o30 = 0.f, o45 = 0.f, o60 = 0.f, o135 = 0.f;

    // P0: load x into regs + padded LDS; col/row partials; 4-angle f16 dots
    if (act) {
        float4 ca = make_float4(0.f, 0.f, 0.f, 0.f);
        float rw[4];
        #pragma unroll
        for (int k = 0; k < 4; ++k) {
            const int unit = l + 49 * k;
            float4 v = ((const float4*)xp)[unit];
            Mv[k] = v;
            ((float4*)sxv)[unit] = v;
            ca.x += v.x; ca.y += v.y; ca.z += v.z; ca.w += v.w;
            rw[k] = (v.x + v.y) + (v.z + v.w);
            half2v vlo = __builtin_bit_cast(half2v, __builtin_amdgcn_cvt_pkrtz(v.x, v.y));
            half2v vhi = __builtin_bit_cast(half2v, __builtin_amdgcn_cvt_pkrtz(v.z, v.w));
            o30  = dot4h(vlo, vhi, mk2p[unit],           o30);
            o45  = dot4h(vlo, vhi, mk2p[196 + unit],     o45);
            o60  = dot4h(vlo, vhi, mk2p[2 * 196 + unit], o60);
            o135 = dot4h(vlo, vhi, mk2p[3 * 196 + unit], o135);
        }
        ((float4*)cp)[l] = ca;
        ((float4*)rp)[l] = make_float4(rw[0], rw[1], rw[2], rw[3]);
    }
    wave_lds_fence();

    // P1: horizontal 7-max; write in place over the row just read (+ ghosts)
    if (act) {
        #pragma unroll
        for (int k = 0; k < 4; ++k) {
            const int r = r0 + 7 * k;
            const float* row = sxv + r * W;
            float4 Lv = *(const float4*)(row + qL);
            float4 Rv = *(const float4*)(row + qR);
            float4 hv = hmax13(Mv[k], Lv, Rv);
            *(float4*)(rm + (r + 3) * W + q) = hv;
            if (k == 0 && r0 == 0) {
                *(float4*)(rm + 0 * W + q) = hv;
                *(float4*)(rm + 1 * W + q) = hv;
                *(float4*)(rm + 2 * W + q) = hv;
            }
            if (k == 3 && r0 == 6) {
                *(float4*)(rm + 31 * W + q) = hv;
                *(float4*)(rm + 32 * W + q) = hv;
                *(float4*)(rm + 33 * W + q) = hv;
            }
        }
    }
    wave_lds_fence();

    // P2: vertical 7-max -> RAW spot moments
    if (act) {
        #pragma unroll
        for (int k = 0; k < 4; ++k) {
            const int r = r0 + 7 * k;
            const float* vb = rm + r * W + q;
            float4 m = *(const float4*)vb;
            m = fmax4(m, *(const float4*)(vb + W));
            m = fmax4(m, *(const float4*)(vb + 2 * W));
            m = fmax4(m, *(const float4*)(vb + 3 * W));
            m = fmax4(m, *(const float4*)(vb + 4 * W));
            m = fmax4(m, *(const float4*)(vb + 5 * W));
            m = fmax4(m, *(const float4*)(vb + 6 * W));
            float s0 = m.x - Mv[k].x;
            float s1 = m.y - Mv[k].y;
            float s2 = m.z - Mv[k].z;
            float s3 = m.w - Mv[k].w;
            fs  += (s0 + s1) + (s2 + s3);
            fss += (s0 * s0 + s1 * s1) + (s2 * s2 + s3 * s3);
        }
    }

    // unified means: lanes 0-27 sum rows (rp), lanes 32-59 sum cols (cp)
    const int idx = l & 31;
    const bool inr = (idx < 28);
    float ssum = 0.f;
    if (inr) {
        const float* bp;
        int st;
        if (l < 32) { bp = rp + (l % 7) * 28 + (l / 7); st = 4; }
        else        { bp = cp + idx;                    st = 28; }
        ssum = ((bp[0] + bp[st]) + (bp[2 * st] + bp[3 * st]))
             + ((bp[4 * st] + bp[5 * st]) + bp[6 * st]);
    }
    float pmean = ssum * (1.f / 28.f);

    // separable 0/90 responses: shared 1-D Gaussian profile
    float g = -1.f + (float)idx * (2.f / 27.f);
    float mg = exp2f(-8.014972687f * g * g);   // (0.5/0.09)*log2e
    float packC = inr ? ssum * mg : 0.f;       // lanes<32: resp0, >=32: resp90

    // unified depthwise conv3 (zero-pad SAME): row path / col path per half
    const float w0 = (l < 32) ? h_w[c * 3]     : v_w[c * 3];
    const float w1 = (l < 32) ? h_w[c * 3 + 1] : v_w[c * 3 + 1];
    const float w2 = (l < 32) ? h_w[c * 3 + 2] : v_w[c * 3 + 2];
    float y = 0.f;
    {
        float pm = __shfl_up(pmean, 1);
        float pp = __shfl_down(pmean, 1);
        if (inr) {
            float a = (idx > 0) ? pm : 0.f;
            float d = (idx < 27) ? pp : 0.f;
            y = w0 * a + w1 * pmean + w2 * d;
            if (l < 32) yh[(size_t)plane * H + idx] = y;
            else        yv[(size_t)plane * W + idx] = y;
        }
    }
    float packA = y;         // lanes<32: yh, >=32: yv
    float packB = y * y;

    // reductions: 6 full chains + 3 packed half chains
    fs   = dpp_sum64(fs);   fss  = dpp_sum64(fss);
    o30  = dpp_sum64(o30);  o45  = dpp_sum64(o45);
    o60  = dpp_sum64(o60);  o135 = dpp_sum64(o135);
    packA = dpp_sum32(packA);
    packB = dpp_sum32(packB);
    packC = dpp_sum32(packC);
    float yhs  = rlane(packA, 31), yvs  = rlane(packA, 63);
    float yhq  = rlane(packB, 31), yvq  = rlane(packB, 63);
    float r0s  = rlane(packC, 31), r90s = rlane(packC, 63);

    if (l == 63) {
        const float s784 = LOG2E / (float)HW;
        float t = sigm2(r0s * s784) + sigm2(o30 * s784) + sigm2(o45 * s784)
                + sigm2(o60 * s784) + sigm2(r90s * s784) + sigm2(o135 * s784);
        at[plane] = t * (1.f / 6.f);
        const float fwc = f_w[c];
        atomicAdd(&acc[0 * C + c], yhs);
        atomicAdd(&acc[1 * C + c], yhq);
        atomicAdd(&acc[2 * C + c], yvs);
        atomicAdd(&acc[3 * C + c], yvq);
        atomicAdd(&acc[4 * C + c], fs * fwc);
        atomicAdd(&acc[5 * C + c], fss * fwc * fwc);
    }
}

// ---------------------------------------------------------------------------
// K2: fold sums into per-channel BN scale/shift, stored padded [C][8].
// ---------------------------------------------------------------------------
__global__ __launch_bounds__(64) void k2_params(
    const float* __restrict__ acc, const float* __restrict__ f_w,
    const float* __restrict__ hg, const float* __restrict__ hb,
    const float* __restrict__ vg, const float* __restrict__ vb,
    const float* __restrict__ fg, const float* __restrict__ fb,
    float* __restrict__ params)
{
    int c = blockIdx.x * 64 + threadIdx.x;
    if (c >= C) return;
    const float inv_nh = 1.f / (float)(B * H);
    const float inv_nf = 1.f / (float)(B * HW);
    float m, v, sc;
    m = acc[c] * inv_nh;
    v = acc[C + c] * inv_nh - m * m;
    sc = hg[c] * rsqrtf(v + 1e-5f);
    params[c * 8 + 0] = sc * LOG2E; params[c * 8 + 1] = (hb[c] - m * sc) * LOG2E;

    m = acc[2 * C + c] * inv_nh;
    v = acc[3 * C + c] * inv_nh - m * m;
    sc = vg[c] * rsqrtf(v + 1e-5f);
    params[c * 8 + 2] = sc * LOG2E; params[c * 8 + 3] = (vb[c] - m * sc) * LOG2E;

    m = acc[4 * C + c] * inv_nf;
    v = acc[5 * C + c] * inv_nf - m * m;
    sc = fg[c] * rsqrtf(v + 1e-5f);
    params[c * 8 + 4] = sc * f_w[c] * LOG2E;
    params[c * 8 + 5] = (fb[c] - m * sc) * LOG2E;
}

// ---------------------------------------------------------------------------
// K3: one wave per plane; union buffer; all four gates; nt stores.
// ---------------------------------------------------------------------------
__global__ __launch_bounds__(256, 8) void k3_apply(
    const float* __restrict__ x,
    const float* __restrict__ yh, const float* __restrict__ yv,
    const float* __restrict__ at, const float* __restrict__ params,
    float* __restrict__ out)
{
    const int tid = threadIdx.x;
    const int wvi = __builtin_amdgcn_readfirstlane(tid >> 6);
    const int l   = tid & 63;
    const int plane = blockIdx.x * 4 + wvi;
    const int c = plane % C;
    const float* xp = x + (size_t)plane * HW;

    __shared__ __align__(16) float uA[4][RMROWS * W];
    float* rm  = uA[wvi];
    float* sxv = rm + 3 * W;

    const int r0 = l / 7;
    const int u  = l - r0 * 7;
    const int q  = u * 4;
    const int qL = u ? q - 4 : 0;
    const int qR = (u < 6) ? q + 4 : 24;
    const bool act = (l < 49);

    const float4 pA = *(const float4*)(params + c * 8);
    const float2 pB = *(const float2*)(params + c * 8 + 4);
    const float atv = at[plane];

    float4 Mv[4];

    if (act) {
        #pragma unroll
        for (int k = 0; k < 4; ++k) {
            const int unit = l + 49 * k;
            Mv[k] = ((const float4*)xp)[unit];
            ((float4*)sxv)[unit] = Mv[k];
        }
    }
    wave_lds_fence();

    if (act) {
        #pragma unroll
        for (int k = 0; k < 4; ++k) {
            const int r = r0 + 7 * k;
            const float* row = sxv + r * W;
            float4 Lv = *(const float4*)(row + qL);
            float4 Rv = *(const float4*)(row + qR);
            float4 hv = hmax13(Mv[k], Lv, Rv);
            *(float4*)(rm + (r + 3) * W + q) = hv;
            if (k == 0 && r0 == 0) {
                *(float4*)(rm + 0 * W + q) = hv;
                *(float4*)(rm + 1 * W + q) = hv;
                *(float4*)(rm + 2 * W + q) = hv;
            }
            if (k == 3 && r0 == 6) {
                *(float4*)(rm + 31 * W + q) = hv;
                *(float4*)(rm + 32 * W + q) = hv;
                *(float4*)(rm + 33 * W + q) = hv;
            }
        }
    }
    wave_lds_fence();

    if (act) {
        float4 yv4;
        yv4.x = yv[(size_t)plane * W + q];
        yv4.y = yv[(size_t)plane * W + q + 1];
        yv4.z = yv[(size_t)plane * W + q + 2];
        yv4.w = yv[(size_t)plane * W + q + 3];
        float4 av;
        av.x = sigm2(pA.z * yv4.x + pA.w);
        av.y = sigm2(pA.z * yv4.y + pA.w);
        av.z = sigm2(pA.z * yv4.z + pA.w);
        av.w = sigm2(pA.z * yv4.w + pA.w);
        nfloat4* op = (nfloat4*)(out + (size_t)plane * HW);
        #pragma unroll
        for (int k = 0; k < 4; ++k) {
            const int r = r0 + 7 * k;
            const float* vb = rm + r * W + q;
            float4 m = *(const float4*)vb;
            m = fmax4(m, *(const float4*)(vb + W));
            m = fmax4(m, *(const float4*)(vb + 2 * W));
            m = fmax4(m, *(const float4*)(vb + 3 * W));
            m = fmax4(m, *(const float4*)(vb + 4 * W));
            m = fmax4(m, *(const float4*)(vb + 5 * W));
            m = fmax4(m, *(const float4*)(vb + 6 * W));
            float ahk = sigm2(pA.x * yh[(size_t)plane * H + r] + pA.y) * atv;
            nfloat4 o;
            o.x = Mv[k].x * ahk * av.x * sigm2(fmaf(pB.x, m.x, fmaf(-pB.x, Mv[k].x, pB.y)));
            o.y = Mv[k].y * ahk * av.y * sigm2(fmaf(pB.x, m.y, fmaf(-pB.x, Mv[k].y, pB.y)));
            o.z = Mv[k].z * ahk * av.z * sigm2(fmaf(pB.x, m.z, fmaf(-pB.x, Mv[k].z, pB.y)));
            o.w = Mv[k].w * ahk * av.w * sigm2(fmaf(pB.x, m.w, fmaf(-pB.x, Mv[k].w, pB.y)));
            __builtin_nontemporal_store(o, &op[l + 49 * k]);
        }
    }
}

// ---------------------------------------------------------------------------
extern "C" void kernel_launch(void* const* d_in, const int* in_sizes, int n_in,
                              void* d_out, int out_size, void* d_ws, size_t ws_size,
                              hipStream_t stream) {
    const float* x   = (const float*)d_in[0];
    const float* h_w = (const float*)d_in[1];
    const float* h_g = (const float*)d_in[2];
    const float* h_b = (const float*)d_in[3];
    const float* v_w = (const float*)d_in[4];
    const float* v_g = (const float*)d_in[5];
    const float* v_b = (const float*)d_in[6];
    const float* f_w = (const float*)d_in[7];
    const float* f_g = (const float*)d_in[8];
    const float* f_b = (const float*)d_in[9];
    float* out = (float*)d_out;
    float* ws = (float*)d_ws;

    // workspace layout (floats)
    _Float16* masksf16 = (_Float16*)ws;  // 4*784 f16 = 6272 B
    float* acc    = ws + 1568;           // 6*576
    float* params = ws + 5024;           // 576*8
    float* at     = ws + 9632;           // B*C
    float* yh     = ws + 83360;          // B*C*H
    float* yv     = ws + 2147744;        // B*C*W

    k0_init<<<14, 256, 0, stream>>>(masksf16, acc);
    k1_stats<<<NPLANE / 4, 256, 0, stream>>>(x, h_w, v_w, f_w, masksf16, yh, yv, at, acc);
    k2_params<<<9, 64, 0, stream>>>(acc, f_w, h_g, h_b, v_g, v_b, f_g, f_b, params);
    k3_apply<<<NPLANE / 4, 256, 0, stream>>>(x, yh, yv, at, params, out);
}

// Round 18
// 169.459 us; speedup vs baseline: 1.3613x; 1.0179x over previous
//
#include <hip/hip_runtime.h>
#include <math.h>

#define B 128
#define C 576
#define H 28
#define W 28
#define HW 784
#define NPLANE (B * C)
#define RMROWS 34   // 3 ghost + 28 + 3 ghost
#define LOG2E 1.4426950408889634f

typedef float nfloat4 __attribute__((ext_vector_type(4)));
typedef _Float16 half2v __attribute__((ext_vector_type(2)));

// sigmoid with log2e pre-folded into the argument: 1/(1+2^(-z))
__device__ __forceinline__ float sigm2(float z2) { return 1.f / (1.f + exp2f(-z2)); }

__device__ __forceinline__ float4 fmax4(float4 a, float4 b) {
    a.x = fmaxf(a.x, b.x); a.y = fmaxf(a.y, b.y);
    a.z = fmaxf(a.z, b.z); a.w = fmaxf(a.w, b.w);
    return a;
}

// horizontal 7-window max for 4 px: Mv center f4, Lv left f4, Rv right f4
__device__ __forceinline__ float4 hmax13(float4 Mv, float4 Lv, float4 Rv) {
    float mm   = fmaxf(fmaxf(Mv.x, Mv.y), fmaxf(Mv.z, Mv.w));
    float l23  = fmaxf(Lv.z, Lv.w);
    float l123 = fmaxf(Lv.y, l23);
    float r01  = fmaxf(Rv.x, Rv.y);
    float r012 = fmaxf(r01, Rv.z);
    float4 o;
    o.x = fmaxf(l123, mm);
    o.y = fmaxf(l23, fmaxf(mm, Rv.x));
    o.z = fmaxf(Lv.w, fmaxf(mm, r01));
    o.w = fmaxf(mm, r012);
    return o;
}

// per-32-half sum via DPP (5 steps): lane31 = sum(0..31), lane63 = sum(32..63)
__device__ __forceinline__ float dpp_sum32(float v) {
    int t;
    t = __builtin_amdgcn_update_dpp(0, __float_as_int(v), 0x111, 0xf, 0xf, true);  v += __int_as_float(t);
    t = __builtin_amdgcn_update_dpp(0, __float_as_int(v), 0x112, 0xf, 0xf, true);  v += __int_as_float(t);
    t = __builtin_amdgcn_update_dpp(0, __float_as_int(v), 0x114, 0xf, 0xf, true);  v += __int_as_float(t);
    t = __builtin_amdgcn_update_dpp(0, __float_as_int(v), 0x118, 0xf, 0xf, true);  v += __int_as_float(t);
    t = __builtin_amdgcn_update_dpp(0, __float_as_int(v), 0x142, 0xa, 0xf, false); v += __int_as_float(t);
    return v;
}

__device__ __forceinline__ float rlane(float v, int n) {
    return __int_as_float(__builtin_amdgcn_readlane(__float_as_int(v), n));
}

// wave-internal LDS write->read ordering
__device__ __forceinline__ void wave_lds_fence() {
    asm volatile("s_waitcnt lgkmcnt(0)" ::: "memory");
    __builtin_amdgcn_sched_barrier(0);
}

// accumulate 4-elem f16 dot into f32
__device__ __forceinline__ float dot4h(half2v vlo, half2v vhi, uint2 md, float acc) {
    half2v mlo = __builtin_bit_cast(half2v, md.x);
    half2v mhi = __builtin_bit_cast(half2v, md.y);
#if __has_builtin(__builtin_amdgcn_fdot2)
    acc = __builtin_amdgcn_fdot2(vlo, mlo, acc, false);
    acc = __builtin_amdgcn_fdot2(vhi, mhi, acc, false);
#else
    acc += (float)vlo.x * (float)mlo.x + (float)vlo.y * (float)mlo.y
         + (float)vhi.x * (float)mhi.x + (float)vhi.y * (float)mhi.y;
#endif
    return acc;
}

// ---------------------------------------------------------------------------
// K0: zero accumulators; f16 masks for angles {30,45,60,135} only.
// ---------------------------------------------------------------------------
__global__ void k0_init(_Float16* __restrict__ masksf16, float* __restrict__ acc) {
    int idx = blockIdx.x * 256 + threadIdx.x;
    if (idx < 6 * C) acc[idx] = 0.f;
    if (idx < 4 * HW) {
        int a = idx / HW;
        int p = idx - a * HW;
        int r = p / W;
        int col = p - r * W;
        const float degs[4] = {30.f, 45.f, 60.f, 135.f};
        float t = degs[a] * 0.017453292519943295f;
        float gy = -1.f + r * (2.f / 27.f);
        float gx = -1.f + col * (2.f / 27.f);
        float perp = gx * (-sinf(t)) + gy * cosf(t);
        float z = perp * (1.f / 0.3f);
        masksf16[idx] = (_Float16)expf(-0.5f * z * z);
    }
}

// ---------------------------------------------------------------------------
// K1: one wave per plane. Lane owns 4 CONSECUTIVE rows (4r0..4r0+3), col
//     group u — vertical 7-max windows overlap: 10 LDS reads + 15 fmax4.
//     Packed half-wave reductions; cross-half pair-packing for full sums.
// ---------------------------------------------------------------------------
__global__ __launch_bounds__(256, 7) void k1_stats(
    const float* __restrict__ x,
    const float* __restrict__ h_w, const float* __restrict__ v_w,
    const float* __restrict__ f_w, const _Float16* __restrict__ masksf16,
    float* __restrict__ yh, float* __restrict__ yv,
    float* __restrict__ at, float* __restrict__ acc)
{
    const int tid = threadIdx.x;
    const int wvi = __builtin_amdgcn_readfirstlane(tid >> 6);
    const int l   = tid & 63;
    const int plane = blockIdx.x * 4 + wvi;
    const int c = plane % C;
    const float* xp = x + (size_t)plane * HW;

    __shared__ __align__(16) float uA[4][RMROWS * W];
    __shared__ __align__(16) float cpA[4][196];
    __shared__ __align__(16) float rpA[4][196];
    float* rm  = uA[wvi];
    float* sxv = rm + 3 * W;
    float* cp  = cpA[wvi];
    float* rp  = rpA[wvi];   // layout [(r0*7+u)][j]: float idx l*4+j

    const int r0 = l / 7;
    const int u  = l - r0 * 7;
    const int q  = u * 4;
    const int qL = u ? q - 4 : 0;
    const int qR = (u < 6) ? q + 4 : 24;
    const bool act = (l < 49);
    const int rbase = 4 * r0;   // first owned row

    const uint2* mk2p = (const uint2*)masksf16;

    float4 Mv[4];
    float fs = 0.f, fss = 0.f;
    float o30 = 0.f, o45 = 0.f, o60 = 0.f, o135 = 0.f;

    // P0: load x rows rbase..rbase+3 into regs + padded LDS; partials; dots
    if (act) {
        float4 ca = make_float4(0.f, 0.f, 0.f, 0.f);
        float rw[4];
        #pragma unroll
        for (int j = 0; j < 4; ++j) {
            const int unit = (rbase + j) * 7 + u;
            float4 v = ((const float4*)xp)[unit];
            Mv[j] = v;
            ((float4*)sxv)[unit] = v;
            ca.x += v.x; ca.y += v.y; ca.z += v.z; ca.w += v.w;
            rw[j] = (v.x + v.y) + (v.z + v.w);
            half2v vlo = __builtin_bit_cast(half2v, __builtin_amdgcn_cvt_pkrtz(v.x, v.y));
            half2v vhi = __builtin_bit_cast(half2v, __builtin_amdgcn_cvt_pkrtz(v.z, v.w));
            o30  = dot4h(vlo, vhi, mk2p[unit],           o30);
            o45  = dot4h(vlo, vhi, mk2p[196 + unit],     o45);
            o60  = dot4h(vlo, vhi, mk2p[2 * 196 + unit], o60);
            o135 = dot4h(vlo, vhi, mk2p[3 * 196 + unit], o135);
        }
        ((float4*)cp)[l] = ca;
        ((float4*)rp)[l] = make_float4(rw[0], rw[1], rw[2], rw[3]);
    }
    wave_lds_fence();

    // P1: horizontal 7-max for rows rbase..rbase+3 (+ ghosts)
    if (act) {
        #pragma unroll
        for (int j = 0; j < 4; ++j) {
            const int r = rbase + j;
            const float* row = sxv + r * W;
            float4 Lv = *(const float4*)(row + qL);
            float4 Rv = *(const float4*)(row + qR);
            float4 hv = hmax13(Mv[j], Lv, Rv);
            *(float4*)(rm + (r + 3) * W + q) = hv;
            if (j == 0 && r0 == 0) {
                *(float4*)(rm + 0 * W + q) = hv;
                *(float4*)(rm + 1 * W + q) = hv;
                *(float4*)(rm + 2 * W + q) = hv;
            }
            if (j == 3 && r0 == 6) {
                *(float4*)(rm + 31 * W + q) = hv;
                *(float4*)(rm + 32 * W + q) = hv;
                *(float4*)(rm + 33 * W + q) = hv;
            }
        }
    }
    wave_lds_fence();

    // P2: shared-tree vertical 7-max over padded rows rbase..rbase+9
    if (act) {
        const float* vb = rm + rbase * W + q;
        float4 v0 = *(const float4*)(vb);
        float4 v1 = *(const float4*)(vb + W);
        float4 v2 = *(const float4*)(vb + 2 * W);
        float4 v3 = *(const float4*)(vb + 3 * W);
        float4 v4 = *(const float4*)(vb + 4 * W);
        float4 v5 = *(const float4*)(vb + 5 * W);
        float4 v6 = *(const float4*)(vb + 6 * W);
        float4 v7 = *(const float4*)(vb + 7 * W);
        float4 v8 = *(const float4*)(vb + 8 * W);
        float4 v9 = *(const float4*)(vb + 9 * W);
        float4 cc = fmax4(fmax4(v3, v4), fmax4(v5, v6));
        float4 m0 = fmax4(fmax4(v0, v1), fmax4(v2, cc));
        float4 m1 = fmax4(fmax4(v1, v2), fmax4(cc, v7));
        float4 m2 = fmax4(fmax4(v2, cc), fmax4(v7, v8));
        float4 m3 = fmax4(fmax4(cc, v7), fmax4(v8, v9));
        float4 mm[4] = {m0, m1, m2, m3};
        #pragma unroll
        for (int j = 0; j < 4; ++j) {
            float s0 = mm[j].x - Mv[j].x;
            float s1 = mm[j].y - Mv[j].y;
            float s2 = mm[j].z - Mv[j].z;
            float s3 = mm[j].w - Mv[j].w;
            fs  += (s0 + s1) + (s2 + s3);
            fss += (s0 * s0 + s1 * s1) + (s2 * s2 + s3 * s3);
        }
    }

    // unified means: lanes 0-27 sum rows (rp), lanes 32-59 sum cols (cp)
    const int idx = l & 31;
    const bool inr = (idx < 28);
    float ssum = 0.f;
    if (inr) {
        if (l < 32) {
            const float* bp = rp + (idx >> 2) * 28 + (idx & 3);   // stride 4
            ssum = ((bp[0] + bp[4]) + (bp[8] + bp[12]))
                 + ((bp[16] + bp[20]) + bp[24]);
        } else {
            const float* bp = cp + idx;                           // stride 28
            ssum = ((bp[0] + bp[28]) + (bp[56] + bp[84]))
                 + ((bp[112] + bp[140]) + bp[168]);
        }
    }
    float pmean = ssum * (1.f / 28.f);

    // separable 0/90 responses: shared 1-D Gaussian profile
    float g = -1.f + (float)idx * (2.f / 27.f);
    float mg = exp2f(-8.014972687f * g * g);   // (0.5/0.09)*log2e
    float packC = inr ? ssum * mg : 0.f;       // lanes<32: resp0, >=32: resp90

    // unified depthwise conv3 (zero-pad SAME): row path / col path per half
    const float w0 = (l < 32) ? h_w[c * 3]     : v_w[c * 3];
    const float w1 = (l < 32) ? h_w[c * 3 + 1] : v_w[c * 3 + 1];
    const float w2 = (l < 32) ? h_w[c * 3 + 2] : v_w[c * 3 + 2];
    float y = 0.f;
    {
        float pm = __shfl_up(pmean, 1);
        float pp = __shfl_down(pmean, 1);
        if (inr) {
            float a = (idx > 0) ? pm : 0.f;
            float d = (idx < 27) ? pp : 0.f;
            y = w0 * a + w1 * pmean + w2 * d;
            if (l < 32) yh[(size_t)plane * H + idx] = y;
            else        yv[(size_t)plane * W + idx] = y;
        }
    }
    float packA = y;         // lanes<32: yh, >=32: yv
    float packB = y * y;

    // reductions: cross-half pair-packing (3 pairs) + 3 packed half chains
    float fsx  = fs  + __shfl_xor(fs,  32, 64);
    float fssx = fss + __shfl_xor(fss, 32, 64);
    float pF = (l < 32) ? fsx : fssx;
    float oAx = o30 + __shfl_xor(o30, 32, 64);
    float oBx = o45 + __shfl_xor(o45, 32, 64);
    float pO1 = (l < 32) ? oAx : oBx;
    float oCx = o60  + __shfl_xor(o60,  32, 64);
    float oDx = o135 + __shfl_xor(o135, 32, 64);
    float pO2 = (l < 32) ? oCx : oDx;

    pF    = dpp_sum32(pF);
    pO1   = dpp_sum32(pO1);
    pO2   = dpp_sum32(pO2);
    packA = dpp_sum32(packA);
    packB = dpp_sum32(packB);
    packC = dpp_sum32(packC);

    float fsT   = rlane(pF, 31),    fssT = rlane(pF, 63);
    float o30T  = rlane(pO1, 31),   o45T = rlane(pO1, 63);
    float o60T  = rlane(pO2, 31),  o135T = rlane(pO2, 63);
    float yhs   = rlane(packA, 31),  yvs = rlane(packA, 63);
    float yhq   = rlane(packB, 31),  yvq = rlane(packB, 63);
    float r0s   = rlane(packC, 31), r90s = rlane(packC, 63);

    if (l == 63) {
        const float s784 = LOG2E / (float)HW;
        float t = sigm2(r0s * s784) + sigm2(o30T * s784) + sigm2(o45T * s784)
                + sigm2(o60T * s784) + sigm2(r90s * s784) + sigm2(o135T * s784);
        at[plane] = t * (1.f / 6.f);
        const float fwc = f_w[c];
        atomicAdd(&acc[0 * C + c], yhs);
        atomicAdd(&acc[1 * C + c], yhq);
        atomicAdd(&acc[2 * C + c], yvs);
        atomicAdd(&acc[3 * C + c], yvq);
        atomicAdd(&acc[4 * C + c], fsT * fwc);
        atomicAdd(&acc[5 * C + c], fssT * fwc * fwc);
    }
}

// ---------------------------------------------------------------------------
// K2: fold sums into per-channel BN scale/shift, stored padded [C][8].
// ---------------------------------------------------------------------------
__global__ __launch_bounds__(64) void k2_params(
    const float* __restrict__ acc, const float* __restrict__ f_w,
    const float* __restrict__ hg, const float* __restrict__ hb,
    const float* __restrict__ vg, const float* __restrict__ vb,
    const float* __restrict__ fg, const float* __restrict__ fb,
    float* __restrict__ params)
{
    int c = blockIdx.x * 64 + threadIdx.x;
    if (c >= C) return;
    const float inv_nh = 1.f / (float)(B * H);
    const float inv_nf = 1.f / (float)(B * HW);
    float m, v, sc;
    m = acc[c] * inv_nh;
    v = acc[C + c] * inv_nh - m * m;
    sc = hg[c] * rsqrtf(v + 1e-5f);
    params[c * 8 + 0] = sc * LOG2E; params[c * 8 + 1] = (hb[c] - m * sc) * LOG2E;

    m = acc[2 * C + c] * inv_nh;
    v = acc[3 * C + c] * inv_nh - m * m;
    sc = vg[c] * rsqrtf(v + 1e-5f);
    params[c * 8 + 2] = sc * LOG2E; params[c * 8 + 3] = (vb[c] - m * sc) * LOG2E;

    m = acc[4 * C + c] * inv_nf;
    v = acc[5 * C + c] * inv_nf - m * m;
    sc = fg[c] * rsqrtf(v + 1e-5f);
    params[c * 8 + 4] = sc * f_w[c] * LOG2E;
    params[c * 8 + 5] = (fb[c] - m * sc) * LOG2E;
}

// ---------------------------------------------------------------------------
// K3: one wave per plane; union buffer; all four gates; nt stores.
// ---------------------------------------------------------------------------
__global__ __launch_bounds__(256, 8) void k3_apply(
    const float* __restrict__ x,
    const float* __restrict__ yh, const float* __restrict__ yv,
    const float* __restrict__ at, const float* __restrict__ params,
    float* __restrict__ out)
{
    const int tid = threadIdx.x;
    const int wvi = __builtin_amdgcn_readfirstlane(tid >> 6);
    const int l   = tid & 63;
    const int plane = blockIdx.x * 4 + wvi;
    const int c = plane % C;
    const float* xp = x + (size_t)plane * HW;

    __shared__ __align__(16) float uA[4][RMROWS * W];
    float* rm  = uA[wvi];
    float* sxv = rm + 3 * W;

    const int r0 = l / 7;
    const int u  = l - r0 * 7;
    const int q  = u * 4;
    const int qL = u ? q - 4 : 0;
    const int qR = (u < 6) ? q + 4 : 24;
    const bool act = (l < 49);

    const float4 pA = *(const float4*)(params + c * 8);
    const float2 pB = *(const float2*)(params + c * 8 + 4);
    const float atv = at[plane];

    float4 Mv[4];

    if (act) {
        #pragma unroll
        for (int k = 0; k < 4; ++k) {
            const int unit = l + 49 * k;
            Mv[k] = ((const float4*)xp)[unit];
            ((float4*)sxv)[unit] = Mv[k];
        }
    }
    wave_lds_fence();

    if (act) {
        #pragma unroll
        for (int k = 0; k < 4; ++k) {
            const int r = r0 + 7 * k;
            const float* row = sxv + r * W;
            float4 Lv = *(const float4*)(row + qL);
            float4 Rv = *(const float4*)(row + qR);
            float4 hv = hmax13(Mv[k], Lv, Rv);
            *(float4*)(rm + (r + 3) * W + q) = hv;
            if (k == 0 && r0 == 0) {
                *(float4*)(rm + 0 * W + q) = hv;
                *(float4*)(rm + 1 * W + q) = hv;
                *(float4*)(rm + 2 * W + q) = hv;
            }
            if (k == 3 && r0 == 6) {
                *(float4*)(rm + 31 * W + q) = hv;
                *(float4*)(rm + 32 * W + q) = hv;
                *(float4*)(rm + 33 * W + q) = hv;
            }
        }
    }
    wave_lds_fence();

    if (act) {
        float4 yv4;
        yv4.x = yv[(size_t)plane * W + q];
        yv4.y = yv[(size_t)plane * W + q + 1];
        yv4.z = yv[(size_t)plane * W + q + 2];
        yv4.w = yv[(size_t)plane * W + q + 3];
        float4 av;
        av.x = sigm2(pA.z * yv4.x + pA.w);
        av.y = sigm2(pA.z * yv4.y + pA.w);
        av.z = sigm2(pA.z * yv4.z + pA.w);
        av.w = sigm2(pA.z * yv4.w + pA.w);
        nfloat4* op = (nfloat4*)(out + (size_t)plane * HW);
        #pragma unroll
        for (int k = 0; k < 4; ++k) {
            const int r = r0 + 7 * k;
            const float* vb = rm + r * W + q;
            float4 m = *(const float4*)vb;
            m = fmax4(m, *(const float4*)(vb + W));
            m = fmax4(m, *(const float4*)(vb + 2 * W));
            m = fmax4(m, *(const float4*)(vb + 3 * W));
            m = fmax4(m, *(const float4*)(vb + 4 * W));
            m = fmax4(m, *(const float4*)(vb + 5 * W));
            m = fmax4(m, *(const float4*)(vb + 6 * W));
            float ahk = sigm2(pA.x * yh[(size_t)plane * H + r] + pA.y) * atv;
            nfloat4 o;
            o.x = Mv[k].x * ahk * av.x * sigm2(fmaf(pB.x, m.x, fmaf(-pB.x, Mv[k].x, pB.y)));
            o.y = Mv[k].y * ahk * av.y * sigm2(fmaf(pB.x, m.y, fmaf(-pB.x, Mv[k].y, pB.y)));
            o.z = Mv[k].z * ahk * av.z * sigm2(fmaf(pB.x, m.z, fmaf(-pB.x, Mv[k].z, pB.y)));
            o.w = Mv[k].w * ahk * av.w * sigm2(fmaf(pB.x, m.w, fmaf(-pB.x, Mv[k].w, pB.y)));
            __builtin_nontemporal_store(o, &op[l + 49 * k]);
        }
    }
}

// ---------------------------------------------------------------------------
extern "C" void kernel_launch(void* const* d_in, const int* in_sizes, int n_in,
                              void* d_out, int out_size, void* d_ws, size_t ws_size,
                              hipStream_t stream) {
    const float* x   = (const float*)d_in[0];
    const float* h_w = (const float*)d_in[1];
    const float* h_g = (const float*)d_in[2];
    const float* h_b = (const float*)d_in[3];
    const float* v_w = (const float*)d_in[4];
    const float* v_g = (const float*)d_in[5];
    const float* v_b = (const float*)d_in[6];
    const float* f_w = (const float*)d_in[7];
    const float* f_g = (const float*)d_in[8];
    const float* f_b = (const float*)d_in[9];
    float* out = (float*)d_out;
    float* ws = (float*)d_ws;

    // workspace layout (floats)
    _Float16* masksf16 = (_Float16*)ws;  // 4*784 f16 = 6272 B
    float* acc    = ws + 1568;           // 6*576
    float* params = ws + 5024;           // 576*8
    float* at     = ws + 9632;           // B*C
    float* yh     = ws + 83360;          // B*C*H
    float* yv     = ws + 2147744;        // B*C*W

    k0_init<<<14, 256, 0, stream>>>(masksf16, acc);
    k1_stats<<<NPLANE / 4, 256, 0, stream>>>(x, h_w, v_w, f_w, masksf16, yh, yv, at, acc);
    k2_params<<<9, 64, 0, stream>>>(acc, f_w, h_g, h_b, v_g, v_b, f_g, f_b, params);
    k3_apply<<<NPLANE / 4, 256, 0, stream>>>(x, yh, yv, at, params, out);
}